// Round 5
// baseline (202.651 us; speedup 1.0000x reference)
//
#include <hip/hip_runtime.h>
#include <cstddef>

#define N_NODES 16384
#define N_EDGES 131072
#define BGR 256
#define NF 64
#define EF 32
#define GF 16

typedef __attribute__((ext_vector_type(8))) short bf16x8;
typedef __attribute__((ext_vector_type(4))) float f32x4;

#define MFMA16(a, b, c) __builtin_amdgcn_mfma_f32_16x16x32_bf16((a), (b), (c), 0, 0, 0)

// fast bf16 round (half-up, <=0.5 ulp): 2 VALU ops
__device__ inline unsigned short f2bf(float f) {
    return (unsigned short)((__builtin_bit_cast(unsigned, f) + 0x8000u) >> 16);
}
__device__ inline float bfs(short x) {
    return __builtin_bit_cast(float, (unsigned)((unsigned short)x) << 16);
}
__device__ inline float bflo(unsigned x) { return __builtin_bit_cast(float, x << 16); }
__device__ inline float bfhi(unsigned x) { return __builtin_bit_cast(float, x & 0xFFFF0000u); }
__device__ inline unsigned pk2(float a, float b) {
    return (unsigned)f2bf(a) | ((unsigned)f2bf(b) << 16);
}

__device__ inline bf16x8 pack8(float4 f0, float4 f1) {
    bf16x8 a;
    a[0] = (short)f2bf(f0.x); a[1] = (short)f2bf(f0.y);
    a[2] = (short)f2bf(f0.z); a[3] = (short)f2bf(f0.w);
    a[4] = (short)f2bf(f1.x); a[5] = (short)f2bf(f1.y);
    a[6] = (short)f2bf(f1.z); a[7] = (short)f2bf(f1.w);
    return a;
}

// --------------------------------------------------------------------- prep
// one launch: weight packing (84) + gproj (128) + receiver hist (512) + bounds (2)
extern "C" __global__ void __launch_bounds__(256)
k_prep(const float* __restrict__ We1, const float* __restrict__ We2,
       const float* __restrict__ Wn1, const float* __restrict__ Win1,
       const float* __restrict__ Wn2, const float* __restrict__ Win2,
       unsigned short* We1p, unsigned short* We2p, unsigned short* Wn1p,
       unsigned short* Win1p, unsigned short* Wn2p, unsigned short* Win2p,
       const float* __restrict__ gf,
       const float* __restrict__ Weg2, const float* __restrict__ be2,
       const float* __restrict__ Wng2, const float* __restrict__ bn2,
       float* __restrict__ gproj_e, float* __restrict__ gproj_n,
       const int* __restrict__ receivers, int* cntR,
       const int* __restrict__ node_graph, const int* __restrict__ edge_graph,
       int* offN, int* offE)
{
    const int bid = blockIdx.x, tid = threadIdx.x;
    if (bid < 84) {
        // pack W [K][N] -> B-frags: frag t=(kt,nt), lane l, elem j =
        // W[kt*32+(l>>4)*8+j][nt*16+(l&15)]; 4 frags per block
        const int fi = bid * 4 + (tid >> 6), l = tid & 63;
        const float* W; unsigned short* P; int N, t;
        if      (fi < 16)  { W = We1;  P = We1p;  N = 256; t = fi;       }
        else if (fi < 80)  { W = We2;  P = We2p;  N = 128; t = fi - 16;  }
        else if (fi < 112) { W = Wn1;  P = Wn1p;  N = 256; t = fi - 80;  }
        else if (fi < 240) { W = Win1; P = Win1p; N = 256; t = fi - 112; }
        else if (fi < 304) { W = Wn2;  P = Wn2p;  N = 128; t = fi - 240; }
        else               { W = Win2; P = Win2p; N = 128; t = fi - 304; }
        const int NT = N / 16;
        const int kt = t / NT, nt = t % NT;
        const int k0 = kt * 32 + (l >> 4) * 8;
        const int col = nt * 16 + (l & 15);
        unsigned short* dst = P + ((size_t)t * 64 + l) * 8;
        #pragma unroll
        for (int j = 0; j < 8; ++j) dst[j] = f2bf(W[(size_t)(k0 + j) * N + col]);
    } else if (bid < 212) {
        // gproj: 2 graphs per block
        const int b = (bid - 84) * 2 + (tid >> 7), t = tid & 127;
        float ge = be2[t], gn = bn2[t];
        #pragma unroll
        for (int j = 0; j < GF; ++j) {
            const float g = gf[b * GF + j];
            ge = fmaf(g, Weg2[j * 128 + t], ge);
            gn = fmaf(g, Wng2[j * 128 + t], gn);
        }
        gproj_e[b * 128 + t] = ge;
        gproj_n[b * 128 + t] = gn;
    } else if (bid < 724) {
        const int i = (bid - 212) * 256 + tid;
        atomicAdd(&cntR[receivers[i]], 1);
    } else {
        // sorted graph ids -> offsets via binary search
        const int g = tid;
        const int* arr = (bid == 725) ? edge_graph : node_graph;
        int* dst       = (bid == 725) ? offE       : offN;
        const int len  = (bid == 725) ? N_EDGES    : N_NODES;
        int lo = 0, hi = len;
        while (lo < hi) {
            const int mid = (lo + hi) >> 1;
            if (arr[mid] < g) lo = mid + 1; else hi = mid;
        }
        dst[g] = lo;
        if (g == 0) dst[256] = len;
    }
}

// ---------------------------------------------------------- parallel scan
extern "C" __global__ void __launch_bounds__(256)
k_scanA(const int* __restrict__ cntR, int* __restrict__ offR, int* __restrict__ bsum)
{
    __shared__ int sm[256];
    const int b = blockIdx.x, t = threadIdx.x;
    const int4 v = *(const int4*)(cntR + b * 1024 + t * 4);
    const int s = v.x + v.y + v.z + v.w;
    sm[t] = s; __syncthreads();
    for (int o = 1; o < 256; o <<= 1) {
        int x = (t >= o) ? sm[t - o] : 0;
        __syncthreads(); sm[t] += x; __syncthreads();
    }
    const int excl = sm[t] - s;
    int4 o;
    o.x = excl; o.y = excl + v.x; o.z = o.y + v.y; o.w = o.z + v.z;
    *(int4*)(offR + b * 1024 + t * 4) = o;
    if (t == 255) bsum[b] = sm[255];
}

extern "C" __global__ void __launch_bounds__(256)
k_scanB(int* __restrict__ offR, const int* __restrict__ bsum)
{
    const int i = blockIdx.x * 256 + threadIdx.x;
    if (i > 16384) return;
    const int g = i >> 10;
    int pre = 0;
    for (int k = 0; k < g; ++k) pre += bsum[k];
    offR[i] = (i < 16384 ? offR[i] : 0) + pre;
}

extern "C" __global__ void __launch_bounds__(256)
k_scatter(const int* __restrict__ receivers, const int* __restrict__ offR,
          int* curR, int* perm)
{
    const int i = blockIdx.x * 256 + threadIdx.x;
    if (i < N_EDGES) {
        const int r = receivers[i];
        const int pos = offR[r] + atomicAdd(&curR[r], 1);
        perm[pos] = i;
    }
}

// ---------------------------------------------------------------- edge block
// 64 edges/block, 2 waves x 32 rows each; ZERO barriers (waves own their rows).
// e1 = relu(ef@We1+be1) -> LDS(swz) + e1g; e2 = relu(e1@We2 + gproj_e) -> e2g.
extern "C" __global__ void __launch_bounds__(128, 2)
k_edge(const float* __restrict__ edge_feats,
       const int* __restrict__ edge_graph,
       const unsigned short* __restrict__ We1p,
       const unsigned short* __restrict__ We2p,
       const float* __restrict__ be1,
       const float* __restrict__ gproj_e,
       unsigned short* __restrict__ e1g,
       unsigned short* __restrict__ e2g)
{
    __shared__ __align__(16) unsigned short e1s[64 * 256];   // 32 KB, swizzled
    const int tid = threadIdx.x;
    const int w = tid >> 6, l = tid & 63;
    const int lr = l & 15, lq = l >> 4;
    const int e0 = blockIdx.x * 64;
    const int R0 = w * 32;
    const int r0 = R0 + lr, r1 = R0 + 16 + lr;     // A rows (local, own wave)

    const int g0 = edge_graph[e0];
    const bool uni = (edge_graph[e0 + 63] == g0);
    int egC[2][4];
    if (!uni) {
        #pragma unroll
        for (int f = 0; f < 2; ++f)
            #pragma unroll
            for (int i = 0; i < 4; ++i)
                egC[f][i] = edge_graph[e0 + R0 + f * 16 + lq * 4 + i];
    }

    // ---- e1: M=32/wave, N=256, K=32 ----
    bf16x8 a0, a1;
    {
        const float* s0 = edge_feats + (size_t)(e0 + r0) * EF + lq * 8;
        a0 = pack8(*(const float4*)s0, *(const float4*)(s0 + 4));
        const float* s1 = edge_feats + (size_t)(e0 + r1) * EF + lq * 8;
        a1 = pack8(*(const float4*)s1, *(const float4*)(s1 + 4));
    }
    char* B = (char*)e1s;
    #pragma unroll
    for (int nt = 0; nt < 16; ++nt) {
        bf16x8 b = *(const bf16x8*)(We1p + ((size_t)nt * 64 + l) * 8);
        f32x4 z = {0.f, 0.f, 0.f, 0.f};
        f32x4 c0 = MFMA16(a0, b, z);
        f32x4 c1 = MFMA16(a1, b, z);
        const int col = nt * 16 + lr;
        const float bias = be1[col];
        #pragma unroll
        for (int f = 0; f < 2; ++f) {
            const f32x4 c = f ? c1 : c0;
            const int rb = R0 + f * 16 + lq * 4;
            #pragma unroll
            for (int i = 0; i < 4; ++i) {
                const int row = rb + i;
                const float v = fmaxf(c[i] + bias, 0.f);
                *(unsigned short*)(B + row * 512 + ((col * 2) ^ ((row & 7) << 4))) = f2bf(v);
            }
        }
    }

    // ---- dump e1 (own 32 rows), coalesced 16B/lane ----
    #pragma unroll
    for (int it = 0; it < 16; ++it) {
        const int flat = it * 1024 + l * 16;
        const int rl = flat >> 9, colb = flat & 511;
        const int row = R0 + rl;
        bf16x8 v = *(const bf16x8*)(B + row * 512 + (colb ^ ((row & 7) << 4)));
        *(bf16x8*)(e1g + (size_t)(e0 + row) * 256 + (colb >> 1)) = v;
    }

    // ---- e2: M=32/wave, N=128, K=256 ----
    f32x4 acc[2][8];
    #pragma unroll
    for (int f = 0; f < 2; ++f)
        #pragma unroll
        for (int nt = 0; nt < 8; ++nt) acc[f][nt] = (f32x4){0.f, 0.f, 0.f, 0.f};
    #pragma unroll
    for (int kt = 0; kt < 8; ++kt) {
        bf16x8 p0 = *(const bf16x8*)(B + r0 * 512 + ((kt * 64 + lq * 16) ^ ((r0 & 7) << 4)));
        bf16x8 p1 = *(const bf16x8*)(B + r1 * 512 + ((kt * 64 + lq * 16) ^ ((r1 & 7) << 4)));
        #pragma unroll
        for (int nt = 0; nt < 8; ++nt) {
            bf16x8 b = *(const bf16x8*)(We2p + ((size_t)(kt * 8 + nt) * 64 + l) * 8);
            acc[0][nt] = MFMA16(p0, b, acc[0][nt]);
            acc[1][nt] = MFMA16(p1, b, acc[1][nt]);
        }
    }

    float gpv[8];
    if (uni) {
        #pragma unroll
        for (int nt = 0; nt < 8; ++nt) gpv[nt] = gproj_e[(size_t)g0 * 128 + nt * 16 + lr];
    }
    #pragma unroll
    for (int nt = 0; nt < 8; ++nt) {
        const int col = nt * 16 + lr;
        #pragma unroll
        for (int f = 0; f < 2; ++f) {
            const int rb = R0 + f * 16 + lq * 4;
            #pragma unroll
            for (int i = 0; i < 4; ++i) {
                const float gv = uni ? gpv[nt] : gproj_e[(size_t)egC[f][i] * 128 + col];
                const float v = fmaxf(acc[f][nt][i] + gv, 0.f);
                const int row = rb + i;
                // reuse front 256B of own row slot (all reads of it already issued)
                *(unsigned short*)(B + row * 512 + ((col * 2) ^ ((row & 7) << 4))) = f2bf(v);
            }
        }
    }
    #pragma unroll
    for (int it = 0; it < 8; ++it) {
        const int flat = it * 1024 + l * 16;
        const int rl = flat >> 8, colb = flat & 255;
        const int row = R0 + rl;
        bf16x8 v = *(const bf16x8*)(B + row * 512 + (colb ^ ((row & 7) << 4)));
        *(bf16x8*)(e2g + (size_t)(e0 + row) * 128 + (colb >> 1)) = v;
    }
}

// ---------------------------------------------- per-node gather-mean (e1,e2)
// wave per node; 2 edges per iteration (half-wave each); shfl-combine.
extern "C" __global__ void __launch_bounds__(256)
k_agg(const unsigned short* __restrict__ e1g,
      const unsigned short* __restrict__ e2g,
      const int* __restrict__ offR, const int* __restrict__ perm,
      unsigned short* __restrict__ mean1, unsigned short* __restrict__ mean2)
{
    const int tid = threadIdx.x, w = tid >> 6, l = tid & 63;
    const int n = blockIdx.x * 4 + w;
    const int g = l >> 5, li = l & 31;
    const int c0 = offR[n], c1 = offR[n + 1];
    float s1[8] = {0.f, 0.f, 0.f, 0.f, 0.f, 0.f, 0.f, 0.f};
    float s2[4] = {0.f, 0.f, 0.f, 0.f};
    int e = c0;
    for (; e + 1 < c1; e += 2) {
        const int eid = perm[e + g];
        bf16x8 a = *(const bf16x8*)(e1g + (size_t)eid * 256 + li * 8);
        #pragma unroll
        for (int j = 0; j < 8; ++j) s1[j] += bfs(a[j]);
        const uint2 b = *(const uint2*)(e2g + (size_t)eid * 128 + li * 4);
        s2[0] += bflo(b.x); s2[1] += bfhi(b.x);
        s2[2] += bflo(b.y); s2[3] += bfhi(b.y);
    }
    if (e < c1 && g == 0) {
        const int eid = perm[e];
        bf16x8 a = *(const bf16x8*)(e1g + (size_t)eid * 256 + li * 8);
        #pragma unroll
        for (int j = 0; j < 8; ++j) s1[j] += bfs(a[j]);
        const uint2 b = *(const uint2*)(e2g + (size_t)eid * 128 + li * 4);
        s2[0] += bflo(b.x); s2[1] += bfhi(b.x);
        s2[2] += bflo(b.y); s2[3] += bfhi(b.y);
    }
    #pragma unroll
    for (int j = 0; j < 8; ++j) s1[j] += __shfl_xor(s1[j], 32);
    #pragma unroll
    for (int j = 0; j < 4; ++j) s2[j] += __shfl_xor(s2[j], 32);
    const float inv = 1.0f / fmaxf((float)(c1 - c0), 1.0f);
    if (g == 0) {
        bf16x8 o1;
        #pragma unroll
        for (int j = 0; j < 8; ++j) o1[j] = (short)f2bf(s1[j] * inv);
        *(bf16x8*)(mean1 + (size_t)n * 256 + li * 8) = o1;
        uint2 o2;
        o2.x = pk2(s2[0] * inv, s2[1] * inv);
        o2.y = pk2(s2[2] * inv, s2[3] * inv);
        *(uint2*)(mean2 + (size_t)n * 128 + li * 4) = o2;
    }
}

// ---------------------------------------------------------------- node block
// 64 nodes/block, 4 waves x 16 rows; ZERO barriers (waves own their rows).
extern "C" __global__ void __launch_bounds__(256, 2)
k_node(const float* __restrict__ node_feats,
       const int* __restrict__ node_graph,
       const unsigned short* __restrict__ Wn1p,
       const unsigned short* __restrict__ Win1p,
       const unsigned short* __restrict__ Wn2p,
       const unsigned short* __restrict__ Win2p,
       const float* __restrict__ bn1,
       const float* __restrict__ gproj_n,
       const unsigned short* __restrict__ mean1,
       const unsigned short* __restrict__ mean2,
       unsigned short* __restrict__ n2g)
{
    __shared__ __align__(16) unsigned short n1s[64 * 256];   // 32 KB, swizzled
    const int tid = threadIdx.x;
    const int wave = tid >> 6, l = tid & 63;
    const int lr = l & 15, lq = l >> 4;
    const int n0 = blockIdx.x * 64;
    const int rowAl = wave * 16 + lr;
    const int rowA  = n0 + rowAl;
    int rC[4], ngC[4];
    #pragma unroll
    for (int i = 0; i < 4; ++i) {
        rC[i]  = wave * 16 + lq * 4 + i;
        ngC[i] = node_graph[n0 + rC[i]];
    }

    // ---- n1: N=256, K=64(nf)+256(mean1) ----
    f32x4 acc[16];
    #pragma unroll
    for (int nt = 0; nt < 16; ++nt) acc[nt] = (f32x4){0.f, 0.f, 0.f, 0.f};
    #pragma unroll
    for (int kt = 0; kt < 2; ++kt) {
        const float* src = node_feats + (size_t)rowA * NF + kt * 32 + lq * 8;
        bf16x8 a = pack8(*(const float4*)src, *(const float4*)(src + 4));
        #pragma unroll
        for (int nt = 0; nt < 16; ++nt)
            acc[nt] = MFMA16(a, *(const bf16x8*)(Wn1p + ((size_t)(kt * 16 + nt) * 64 + l) * 8), acc[nt]);
    }
    #pragma unroll
    for (int kt = 0; kt < 8; ++kt) {
        bf16x8 a = *(const bf16x8*)(mean1 + (size_t)rowA * 256 + kt * 32 + lq * 8);
        #pragma unroll
        for (int nt = 0; nt < 16; ++nt)
            acc[nt] = MFMA16(a, *(const bf16x8*)(Win1p + ((size_t)(kt * 16 + nt) * 64 + l) * 8), acc[nt]);
    }
    char* n1b = (char*)n1s;
    #pragma unroll
    for (int nt = 0; nt < 16; ++nt) {
        const int col = nt * 16 + lr;
        const float bias = bn1[col];
        #pragma unroll
        for (int i = 0; i < 4; ++i) {
            const float v = fmaxf(acc[nt][i] + bias, 0.f);
            const int row = rC[i];
            *(unsigned short*)(n1b + row * 512 + ((col * 2) ^ ((row & 7) << 4))) = f2bf(v);
        }
    }

    // ---- n2: N=128, K=256(n1)+128(mean2) ----
    f32x4 acc2[8];
    #pragma unroll
    for (int nt = 0; nt < 8; ++nt) acc2[nt] = (f32x4){0.f, 0.f, 0.f, 0.f};
    #pragma unroll
    for (int kt = 0; kt < 8; ++kt) {
        bf16x8 a = *(const bf16x8*)(n1b + rowAl * 512 +
                                    ((kt * 64 + lq * 16) ^ ((rowAl & 7) << 4)));
        #pragma unroll
        for (int nt = 0; nt < 8; ++nt)
            acc2[nt] = MFMA16(a, *(const bf16x8*)(Wn2p + ((size_t)(kt * 8 + nt) * 64 + l) * 8), acc2[nt]);
    }
    #pragma unroll
    for (int kt = 0; kt < 4; ++kt) {
        bf16x8 a = *(const bf16x8*)(mean2 + (size_t)rowA * 128 + kt * 32 + lq * 8);
        #pragma unroll
        for (int nt = 0; nt < 8; ++nt)
            acc2[nt] = MFMA16(a, *(const bf16x8*)(Win2p + ((size_t)(kt * 8 + nt) * 64 + l) * 8), acc2[nt]);
    }
    #pragma unroll
    for (int nt = 0; nt < 8; ++nt) {
        const int col = nt * 16 + lr;
        #pragma unroll
        for (int i = 0; i < 4; ++i) {
            const float v = fmaxf(acc2[nt][i] + gproj_n[(size_t)ngC[i] * 128 + col], 0.f);
            const int row = rC[i];
            *(unsigned short*)(n1b + row * 512 + ((col * 2) ^ ((row & 7) << 4))) = f2bf(v);
        }
    }
    #pragma unroll
    for (int it = 0; it < 4; ++it) {
        const int flat = it * 1024 + l * 16;
        const int rl = flat >> 8, colb = flat & 255;
        const int row = wave * 16 + rl;
        bf16x8 v = *(const bf16x8*)(n1b + row * 512 + (colb ^ ((row & 7) << 4)));
        *(bf16x8*)(n2g + (size_t)(n0 + row) * 128 + (colb >> 1)) = v;
    }
}

// -------------------------------------------------------------- global block
extern "C" __global__ void __launch_bounds__(256)
k_global(const float* __restrict__ global_feats,
         const float* __restrict__ Ugn, const float* __restrict__ Uge,
         const float* __restrict__ Ugg, const float* __restrict__ bg,
         const float* __restrict__ Wm, const float* __restrict__ bm,
         const float* __restrict__ Ws, const float* __restrict__ bs,
         const unsigned short* __restrict__ n2g,
         const unsigned short* __restrict__ e2g,
         const int* __restrict__ offN, const int* __restrict__ offE,
         float* __restrict__ out)
{
    __shared__ float redn[16][128], rede[16][128];
    __shared__ float mn[128], me[128], gs[256];
    const int b = blockIdx.x, tid = threadIdx.x;
    const int c = tid & 15, rp = tid >> 4;     // 8 cols/thread, 16-way rows
    float sn[8] = {0.f, 0.f, 0.f, 0.f, 0.f, 0.f, 0.f, 0.f};
    float se[8] = {0.f, 0.f, 0.f, 0.f, 0.f, 0.f, 0.f, 0.f};
    const int nb = offN[b], ne = offN[b + 1];
    for (int r = nb + rp; r < ne; r += 16) {
        bf16x8 v = *(const bf16x8*)(n2g + (size_t)r * 128 + c * 8);
        #pragma unroll
        for (int j = 0; j < 8; ++j) sn[j] += bfs(v[j]);
    }
    const int eb = offE[b], ee = offE[b + 1];
    for (int r = eb + rp; r < ee; r += 16) {
        bf16x8 v = *(const bf16x8*)(e2g + (size_t)r * 128 + c * 8);
        #pragma unroll
        for (int j = 0; j < 8; ++j) se[j] += bfs(v[j]);
    }
    #pragma unroll
    for (int j = 0; j < 8; ++j) { redn[rp][c * 8 + j] = sn[j]; rede[rp][c * 8 + j] = se[j]; }
    __syncthreads();
    if (tid < 128) {
        float s = 0.f;
        #pragma unroll
        for (int k = 0; k < 16; ++k) s += redn[k][tid];
        mn[tid] = s / fmaxf((float)(ne - nb), 1.0f);
    } else {
        const int t = tid - 128;
        float s = 0.f;
        #pragma unroll
        for (int k = 0; k < 16; ++k) s += rede[k][t];
        me[t] = s / fmaxf((float)(ee - eb), 1.0f);
    }
    __syncthreads();

    const int h = tid;   // H = 256
    float u = bg[h];
    for (int k = 0; k < 128; ++k) u = fmaf(mn[k], Ugn[k * 256 + h], u);
    for (int k = 0; k < 128; ++k) u = fmaf(me[k], Uge[k * 256 + h], u);
    #pragma unroll
    for (int j = 0; j < GF; ++j) u = fmaf(global_feats[b * GF + j], Ugg[j * 256 + h], u);
    gs[h] = fmaxf(u, 0.0f);
    __syncthreads();

    if (tid < 16) {
        const int a = tid & 7;
        const int which = tid >> 3;      // 0 = mean, 1 = log_std
        const float* W = which ? Ws : Wm;
        float acc = which ? bs[a] : bm[a];
        for (int k = 0; k < 256; ++k) acc = fmaf(gs[k], W[k * 8 + a], acc);
        if (which) acc = fminf(fmaxf(acc, -20.0f), 2.0f);
        out[which * 2048 + b * 8 + a] = acc;
    }
}

extern "C" void kernel_launch(void* const* d_in, const int* in_sizes, int n_in,
                              void* d_out, int out_size, void* d_ws, size_t ws_size,
                              hipStream_t stream)
{
    (void)in_sizes; (void)n_in; (void)out_size; (void)ws_size;
    const float* node_feats   = (const float*)d_in[0];
    const float* edge_feats   = (const float*)d_in[1];
    const float* global_feats = (const float*)d_in[2];
    const int*   receivers    = (const int*)d_in[3];
    const int*   node_graph   = (const int*)d_in[4];
    const int*   edge_graph   = (const int*)d_in[5];
    const float* We1 = (const float*)d_in[6];
    const float* be1 = (const float*)d_in[7];
    const float* Wn1 = (const float*)d_in[8];
    const float* Win1= (const float*)d_in[9];
    const float* bn1 = (const float*)d_in[10];
    const float* We2 = (const float*)d_in[11];
    const float* Weg2= (const float*)d_in[12];
    const float* be2 = (const float*)d_in[13];
    const float* Wn2 = (const float*)d_in[14];
    const float* Win2= (const float*)d_in[15];
    const float* Wng2= (const float*)d_in[16];
    const float* bn2 = (const float*)d_in[17];
    const float* Ugn = (const float*)d_in[18];
    const float* Uge = (const float*)d_in[19];
    const float* Ugg = (const float*)d_in[20];
    const float* bg  = (const float*)d_in[21];
    const float* Wm  = (const float*)d_in[22];
    const float* bm  = (const float*)d_in[23];
    const float* Ws  = (const float*)d_in[24];
    const float* bs  = (const float*)d_in[25];

    char* p = (char*)d_ws;
    auto alloc = [&](size_t bytes) -> char* {
        char* r = p; p += (bytes + 255) & ~(size_t)255; return r;
    };
    // zeroed region (contiguous, at the front)
    int* cntR  = (int*)alloc(16384 * 4);
    int* curR  = (int*)alloc(16384 * 4);
    const size_t zero_bytes = (size_t)(p - (char*)d_ws);
    // overwritten-every-call region
    int* offR = (int*)alloc(16385 * 4);
    int* bsum = (int*)alloc(16 * 4);
    int* offN = (int*)alloc(257 * 4);
    int* offE = (int*)alloc(257 * 4);
    int* perm = (int*)alloc((size_t)N_EDGES * 4);
    float* gproj_e = (float*)alloc((size_t)BGR * 128 * 4);
    float* gproj_n = (float*)alloc((size_t)BGR * 128 * 4);
    unsigned short* We1p  = (unsigned short*)alloc((size_t)32 * 256 * 2);
    unsigned short* We2p  = (unsigned short*)alloc((size_t)256 * 128 * 2);
    unsigned short* Wn1p  = (unsigned short*)alloc((size_t)64 * 256 * 2);
    unsigned short* Win1p = (unsigned short*)alloc((size_t)256 * 256 * 2);
    unsigned short* Wn2p  = (unsigned short*)alloc((size_t)256 * 128 * 2);
    unsigned short* Win2p = (unsigned short*)alloc((size_t)128 * 128 * 2);
    unsigned short* e1g   = (unsigned short*)alloc((size_t)N_EDGES * 256 * 2);
    unsigned short* e2g   = (unsigned short*)alloc((size_t)N_EDGES * 128 * 2);
    unsigned short* n2g   = (unsigned short*)alloc((size_t)N_NODES * 128 * 2);
    unsigned short* mean1 = (unsigned short*)alloc((size_t)N_NODES * 256 * 2);
    unsigned short* mean2 = (unsigned short*)alloc((size_t)N_NODES * 128 * 2);

    hipMemsetAsync(d_ws, 0, zero_bytes, stream);

    k_prep<<<726, 256, 0, stream>>>(
        We1, We2, Wn1, Win1, Wn2, Win2,
        We1p, We2p, Wn1p, Win1p, Wn2p, Win2p,
        global_feats, Weg2, be2, Wng2, bn2, gproj_e, gproj_n,
        receivers, cntR, node_graph, edge_graph, offN, offE);
    k_scanA<<<16, 256, 0, stream>>>(cntR, offR, bsum);
    k_scanB<<<65, 256, 0, stream>>>(offR, bsum);
    k_scatter<<<N_EDGES / 256, 256, 0, stream>>>(receivers, offR, curR, perm);
    k_edge<<<N_EDGES / 64, 128, 0, stream>>>(
        edge_feats, edge_graph, We1p, We2p, be1, gproj_e, e1g, e2g);
    k_agg<<<N_NODES / 4, 256, 0, stream>>>(e1g, e2g, offR, perm, mean1, mean2);
    k_node<<<N_NODES / 64, 256, 0, stream>>>(
        node_feats, node_graph, Wn1p, Win1p, Wn2p, Win2p, bn1, gproj_n,
        mean1, mean2, n2g);
    k_global<<<BGR, 256, 0, stream>>>(
        global_feats, Ugn, Uge, Ugg, bg, Wm, bm, Ws, bs,
        n2g, e2g, offN, offE, (float*)d_out);
}

// Round 7
// 116.059 us; speedup vs baseline: 1.7461x; 1.7461x over previous
//
#include <hip/hip_runtime.h>
#include <cstddef>

#define N_NODES 16384
#define N_EDGES 131072
#define BGR 256
#define NF 64
#define EF 32
#define GF 16

typedef __attribute__((ext_vector_type(8))) short bf16x8;
typedef __attribute__((ext_vector_type(4))) float f32x4;

#define MFMA16(a, b, c) __builtin_amdgcn_mfma_f32_16x16x32_bf16((a), (b), (c), 0, 0, 0)
__device__ const f32x4 ZERO4 = {0.f, 0.f, 0.f, 0.f};

// fast bf16 round (half-up, <=0.5 ulp): 2 VALU ops
__device__ inline unsigned short f2bf(float f) {
    return (unsigned short)((__builtin_bit_cast(unsigned, f) + 0x8000u) >> 16);
}
__device__ inline float bfs(short x) {
    return __builtin_bit_cast(float, (unsigned)((unsigned short)x) << 16);
}

__device__ inline bf16x8 pack8(float4 f0, float4 f1) {
    bf16x8 a;
    a[0] = (short)f2bf(f0.x); a[1] = (short)f2bf(f0.y);
    a[2] = (short)f2bf(f0.z); a[3] = (short)f2bf(f0.w);
    a[4] = (short)f2bf(f1.x); a[5] = (short)f2bf(f1.y);
    a[6] = (short)f2bf(f1.z); a[7] = (short)f2bf(f1.w);
    return a;
}

// --------------------------------------------------------------------- prep
// one launch: weight packing (84) + gproj (128) + receiver hist (512) + bounds (2)
extern "C" __global__ void __launch_bounds__(256)
k_prep(const float* __restrict__ We1, const float* __restrict__ We2,
       const float* __restrict__ Wn1, const float* __restrict__ Win1,
       const float* __restrict__ Wn2, const float* __restrict__ Win2,
       unsigned short* We1p, unsigned short* We2p, unsigned short* Wn1p,
       unsigned short* Win1p, unsigned short* Wn2p, unsigned short* Win2p,
       const float* __restrict__ gf,
       const float* __restrict__ Weg2, const float* __restrict__ be2,
       const float* __restrict__ Wng2, const float* __restrict__ bn2,
       float* __restrict__ gproj_e, float* __restrict__ gproj_n,
       const int* __restrict__ receivers, int* cntR,
       const int* __restrict__ node_graph, const int* __restrict__ edge_graph,
       int* offN, int* offE)
{
    const int bid = blockIdx.x, tid = threadIdx.x;
    if (bid < 84) {
        // pack W [K][N] -> B-frags: frag t=(kt,nt), lane l, elem j =
        // W[kt*32+(l>>4)*8+j][nt*16+(l&15)]; 4 frags per block
        const int fi = bid * 4 + (tid >> 6), l = tid & 63;
        const float* W; unsigned short* P; int N, t;
        if      (fi < 16)  { W = We1;  P = We1p;  N = 256; t = fi;       }
        else if (fi < 80)  { W = We2;  P = We2p;  N = 128; t = fi - 16;  }
        else if (fi < 112) { W = Wn1;  P = Wn1p;  N = 256; t = fi - 80;  }
        else if (fi < 240) { W = Win1; P = Win1p; N = 256; t = fi - 112; }
        else if (fi < 304) { W = Wn2;  P = Wn2p;  N = 128; t = fi - 240; }
        else               { W = Win2; P = Win2p; N = 128; t = fi - 304; }
        const int NT = N / 16;
        const int kt = t / NT, nt = t % NT;
        const int k0 = kt * 32 + (l >> 4) * 8;
        const int col = nt * 16 + (l & 15);
        unsigned short* dst = P + ((size_t)t * 64 + l) * 8;
        #pragma unroll
        for (int j = 0; j < 8; ++j) dst[j] = f2bf(W[(size_t)(k0 + j) * N + col]);
    } else if (bid < 212) {
        // gproj: 2 graphs per block
        const int b = (bid - 84) * 2 + (tid >> 7), t = tid & 127;
        float ge = be2[t], gn = bn2[t];
        #pragma unroll
        for (int j = 0; j < GF; ++j) {
            const float g = gf[b * GF + j];
            ge = fmaf(g, Weg2[j * 128 + t], ge);
            gn = fmaf(g, Wng2[j * 128 + t], gn);
        }
        gproj_e[b * 128 + t] = ge;
        gproj_n[b * 128 + t] = gn;
    } else if (bid < 724) {
        const int i = (bid - 212) * 256 + tid;
        atomicAdd(&cntR[receivers[i]], 1);
    } else {
        // sorted graph ids -> offsets via binary search
        const int g = tid;
        const int* arr = (bid == 725) ? edge_graph : node_graph;
        int* dst       = (bid == 725) ? offE       : offN;
        const int len  = (bid == 725) ? N_EDGES    : N_NODES;
        int lo = 0, hi = len;
        while (lo < hi) {
            const int mid = (lo + hi) >> 1;
            if (arr[mid] < g) lo = mid + 1; else hi = mid;
        }
        dst[g] = lo;
        if (g == 0) dst[256] = len;
    }
}

// ---------------------------------------------------------- parallel scan
extern "C" __global__ void __launch_bounds__(256)
k_scanA(const int* __restrict__ cntR, int* __restrict__ offR, int* __restrict__ bsum)
{
    __shared__ int sm[256];
    const int b = blockIdx.x, t = threadIdx.x;
    const int4 v = *(const int4*)(cntR + b * 1024 + t * 4);
    const int s = v.x + v.y + v.z + v.w;
    sm[t] = s; __syncthreads();
    for (int o = 1; o < 256; o <<= 1) {
        int x = (t >= o) ? sm[t - o] : 0;
        __syncthreads(); sm[t] += x; __syncthreads();
    }
    const int excl = sm[t] - s;
    int4 o;
    o.x = excl; o.y = excl + v.x; o.z = o.y + v.y; o.w = o.z + v.z;
    *(int4*)(offR + b * 1024 + t * 4) = o;
    if (t == 255) bsum[b] = sm[255];
}

extern "C" __global__ void __launch_bounds__(256)
k_scanB(int* __restrict__ offR, const int* __restrict__ bsum)
{
    const int i = blockIdx.x * 256 + threadIdx.x;
    if (i > 16384) return;
    const int g = i >> 10;
    int pre = 0;
    for (int k = 0; k < g; ++k) pre += bsum[k];
    offR[i] = (i < 16384 ? offR[i] : 0) + pre;
}

extern "C" __global__ void __launch_bounds__(256)
k_scatter(const int* __restrict__ receivers, const int* __restrict__ offR,
          int* curR, int* perm)
{
    const int i = blockIdx.x * 256 + threadIdx.x;
    if (i < N_EDGES) {
        const int r = receivers[i];
        const int pos = offR[r] + atomicAdd(&curR[r], 1);
        perm[pos] = i;
    }
}

// ---------------------------------------------------------------- edge block
// Processes edges in PERM (receiver-sorted) order. 64 edges/block, 4 waves.
// Waves tile N (share A via LDS): each B-frag loaded once per BLOCK.
// e1 -> e1p (perm-contig); e2 -> e2p (perm-contig) + e2g (original order).
extern "C" __global__ void __launch_bounds__(256)
k_edge(const float* __restrict__ edge_feats,
       const int* __restrict__ perm,
       const int* __restrict__ edge_graph,
       const unsigned short* __restrict__ We1p,
       const unsigned short* __restrict__ We2p,
       const float* __restrict__ be1,
       const float* __restrict__ gproj_e,
       unsigned short* __restrict__ e1p,
       unsigned short* __restrict__ e2p,
       unsigned short* __restrict__ e2g)
{
    __shared__ __align__(16) unsigned short e1s[64 * 256];   // 32 KB, swizzled
    const int tid = threadIdx.x;
    const int w = tid >> 6, l = tid & 63;
    const int lr = l & 15, lq = l >> 4;
    const int e0 = blockIdx.x * 64;
    char* B = (char*)e1s;

    int eidA[4];
    int egC[4][4];
    #pragma unroll
    for (int g = 0; g < 4; ++g) eidA[g] = perm[e0 + g * 16 + lr];
    #pragma unroll
    for (int g = 0; g < 4; ++g)
        #pragma unroll
        for (int i = 0; i < 4; ++i)
            egC[g][i] = edge_graph[perm[e0 + g * 16 + lq * 4 + i]];

    // ---- e1: M=64 (4 row-groups, A shared), wave owns nt = w*4..w*4+3 ----
    bf16x8 a[4];
    #pragma unroll
    for (int g = 0; g < 4; ++g) {
        const float* s = edge_feats + (size_t)eidA[g] * EF + lq * 8;
        a[g] = pack8(*(const float4*)s, *(const float4*)(s + 4));
    }
    #pragma unroll
    for (int j = 0; j < 4; ++j) {
        const int nt = w * 4 + j;
        bf16x8 bfr = *(const bf16x8*)(We1p + ((size_t)nt * 64 + l) * 8);
        const int col = nt * 16 + lr;
        const float bias = be1[col];
        #pragma unroll
        for (int g = 0; g < 4; ++g) {
            f32x4 c = MFMA16(a[g], bfr, ZERO4);
            #pragma unroll
            for (int i = 0; i < 4; ++i) {
                const int row = g * 16 + lq * 4 + i;
                const float v = fmaxf(c[i] + bias, 0.f);
                *(unsigned short*)(B + row * 512 + ((col * 2) ^ ((row & 7) << 4))) = f2bf(v);
            }
        }
    }
    __syncthreads();

    // ---- dump e1 -> e1p (perm-contiguous), 16B/lane ----
    #pragma unroll
    for (int it = 0; it < 8; ++it) {
        const int flat = it * 4096 + tid * 16;
        const int row = flat >> 9, colb = flat & 511;
        bf16x8 v = *(const bf16x8*)(B + row * 512 + (colb ^ ((row & 7) << 4)));
        *(bf16x8*)(e1p + (size_t)(e0 + row) * 256 + (colb >> 1)) = v;
    }

    // ---- e2: K=256 from LDS (all rows), wave owns nt = w*2, w*2+1 ----
    f32x4 acc[4][2];
    #pragma unroll
    for (int g = 0; g < 4; ++g) {
        acc[g][0] = ZERO4;
        acc[g][1] = ZERO4;
    }
    #pragma unroll
    for (int kt = 0; kt < 8; ++kt) {
        bf16x8 pA[4];
        #pragma unroll
        for (int g = 0; g < 4; ++g) {
            const int row = g * 16 + lr;
            pA[g] = *(const bf16x8*)(B + row * 512 + ((kt * 64 + lq * 16) ^ ((lr & 7) << 4)));
        }
        #pragma unroll
        for (int j = 0; j < 2; ++j) {
            const int nt = w * 2 + j;
            bf16x8 bfr = *(const bf16x8*)(We2p + ((size_t)(kt * 8 + nt) * 64 + l) * 8);
            #pragma unroll
            for (int g = 0; g < 4; ++g) acc[g][j] = MFMA16(pA[g], bfr, acc[g][j]);
        }
    }
    __syncthreads();   // all LDS reads done before overwrite

    #pragma unroll
    for (int j = 0; j < 2; ++j) {
        const int nt = w * 2 + j, col = nt * 16 + lr;
        #pragma unroll
        for (int g = 0; g < 4; ++g)
            #pragma unroll
            for (int i = 0; i < 4; ++i) {
                const int row = g * 16 + lq * 4 + i;
                const float v = fmaxf(acc[g][j][i] + gproj_e[(size_t)egC[g][i] * 128 + col], 0.f);
                *(unsigned short*)(B + row * 512 + ((col * 2) ^ ((row & 7) << 4))) = f2bf(v);
            }
    }
    __syncthreads();
    #pragma unroll
    for (int it = 0; it < 4; ++it) {
        const int flat = it * 4096 + tid * 16;
        const int row = flat >> 8, colb = flat & 255;
        bf16x8 v = *(const bf16x8*)(B + row * 512 + (colb ^ ((row & 7) << 4)));
        const int eid = perm[e0 + row];
        *(bf16x8*)(e2p + (size_t)(e0 + row) * 128 + (colb >> 1)) = v;
        *(bf16x8*)(e2g + (size_t)eid * 128 + (colb >> 1)) = v;
    }
}

// -------------------------------------------- fused aggregate + node block
// 16 nodes/block (1024 blocks), 4 waves. Phase A: stream perm-contiguous
// e1p/e2p ranges -> per-node means in LDS. Phase B/C: n1, n2 GEMMs (waves
// tile N). n2 -> n2g. No atomics, no mean round-trip.
extern "C" __global__ void __launch_bounds__(256)
k_nodeagg(const float* __restrict__ node_feats,
          const int* __restrict__ node_graph,
          const int* __restrict__ offR,
          const unsigned short* __restrict__ e1p,
          const unsigned short* __restrict__ e2p,
          const unsigned short* __restrict__ Wn1p,
          const unsigned short* __restrict__ Win1p,
          const unsigned short* __restrict__ Wn2p,
          const unsigned short* __restrict__ Win2p,
          const float* __restrict__ bn1,
          const float* __restrict__ gproj_n,
          unsigned short* __restrict__ n2g)
{
    __shared__ __align__(16) unsigned short m1s[16 * 256];   // 8 KB  mean1
    __shared__ __align__(16) unsigned short m2s[16 * 128];   // 4 KB  mean2 / n2 tile
    __shared__ __align__(16) unsigned short n1s[16 * 256];   // 8 KB  n1
    const int tid = threadIdx.x;
    const int w = tid >> 6, l = tid & 63;
    const int lr = l & 15, lq = l >> 4;
    const int n0 = blockIdx.x * 16;
    char* M1 = (char*)m1s; char* M2 = (char*)m2s; char* N1 = (char*)n1s;

    // ---- phase A: aggregate; wave w handles nodes w*4..w*4+3 ----
    const int half = l >> 5, li = l & 31, q = l >> 4;
    for (int jn = 0; jn < 4; ++jn) {
        const int rn = w * 4 + jn, n = n0 + rn;
        const int c0 = offR[n], c1 = offR[n + 1];
        float s1[8] = {0.f, 0.f, 0.f, 0.f, 0.f, 0.f, 0.f, 0.f};
        float s2[8] = {0.f, 0.f, 0.f, 0.f, 0.f, 0.f, 0.f, 0.f};
        int r = c0;
        for (; r + 2 <= c1; r += 2) {                 // e1p: 2 rows (512B) /iter
            bf16x8 v = *(const bf16x8*)(e1p + (size_t)(r + half) * 256 + li * 8);
            #pragma unroll
            for (int j = 0; j < 8; ++j) s1[j] += bfs(v[j]);
        }
        if (r < c1 && half == 0) {
            bf16x8 v = *(const bf16x8*)(e1p + (size_t)r * 256 + li * 8);
            #pragma unroll
            for (int j = 0; j < 8; ++j) s1[j] += bfs(v[j]);
        }
        r = c0;
        for (; r + 4 <= c1; r += 4) {                 // e2p: 4 rows (256B) /iter
            bf16x8 v = *(const bf16x8*)(e2p + (size_t)(r + q) * 128 + lr * 8);
            #pragma unroll
            for (int j = 0; j < 8; ++j) s2[j] += bfs(v[j]);
        }
        if (r + q < c1) {
            bf16x8 v = *(const bf16x8*)(e2p + (size_t)(r + q) * 128 + lr * 8);
            #pragma unroll
            for (int j = 0; j < 8; ++j) s2[j] += bfs(v[j]);
        }
        #pragma unroll
        for (int j = 0; j < 8; ++j) s1[j] += __shfl_xor(s1[j], 32);
        #pragma unroll
        for (int j = 0; j < 8; ++j) {
            s2[j] += __shfl_xor(s2[j], 16);
            s2[j] += __shfl_xor(s2[j], 32);
        }
        const float inv = 1.0f / fmaxf((float)(c1 - c0), 1.0f);
        if (half == 0) {
            bf16x8 o;
            #pragma unroll
            for (int j = 0; j < 8; ++j) o[j] = (short)f2bf(s1[j] * inv);
            *(bf16x8*)(M1 + rn * 512 + ((li * 16) ^ ((rn & 7) << 4))) = o;
        }
        if (l < 16) {
            bf16x8 o;
            #pragma unroll
            for (int j = 0; j < 8; ++j) o[j] = (short)f2bf(s2[j] * inv);
            *(bf16x8*)(M2 + rn * 256 + ((l * 16) ^ ((rn & 7) << 4))) = o;
        }
    }
    __syncthreads();

    // ---- phase B: n1 (M=16, K=64+256), wave owns nt = w*4..w*4+3 ----
    bf16x8 A1[10];
    #pragma unroll
    for (int kt = 0; kt < 2; ++kt) {
        const float* s = node_feats + (size_t)(n0 + lr) * NF + kt * 32 + lq * 8;
        A1[kt] = pack8(*(const float4*)s, *(const float4*)(s + 4));
    }
    #pragma unroll
    for (int kt = 0; kt < 8; ++kt)
        A1[2 + kt] = *(const bf16x8*)(M1 + lr * 512 + ((kt * 64 + lq * 16) ^ ((lr & 7) << 4)));
    #pragma unroll
    for (int j = 0; j < 4; ++j) {
        const int nt = w * 4 + j, col = nt * 16 + lr;
        f32x4 c = ZERO4;
        #pragma unroll
        for (int kt = 0; kt < 2; ++kt)
            c = MFMA16(A1[kt], *(const bf16x8*)(Wn1p + ((size_t)(kt * 16 + nt) * 64 + l) * 8), c);
        #pragma unroll
        for (int kt = 0; kt < 8; ++kt)
            c = MFMA16(A1[2 + kt], *(const bf16x8*)(Win1p + ((size_t)(kt * 16 + nt) * 64 + l) * 8), c);
        const float bias = bn1[col];
        #pragma unroll
        for (int i = 0; i < 4; ++i) {
            const int row = lq * 4 + i;
            const float v = fmaxf(c[i] + bias, 0.f);
            *(unsigned short*)(N1 + row * 512 + ((col * 2) ^ ((row & 7) << 4))) = f2bf(v);
        }
    }
    __syncthreads();

    // ---- phase C: n2 (M=16, K=256+128), wave owns nt = w*2, w*2+1 ----
    int ngv[4];
    #pragma unroll
    for (int i = 0; i < 4; ++i) ngv[i] = node_graph[n0 + lq * 4 + i];
    f32x4 acc[2];
    acc[0] = ZERO4;
    acc[1] = ZERO4;
    #pragma unroll
    for (int kt = 0; kt < 8; ++kt) {
        bf16x8 Aa = *(const bf16x8*)(N1 + lr * 512 + ((kt * 64 + lq * 16) ^ ((lr & 7) << 4)));
        #pragma unroll
        for (int j = 0; j < 2; ++j) {
            const int nt = w * 2 + j;
            acc[j] = MFMA16(Aa, *(const bf16x8*)(Wn2p + ((size_t)(kt * 8 + nt) * 64 + l) * 8), acc[j]);
        }
    }
    #pragma unroll
    for (int kt = 0; kt < 4; ++kt) {
        bf16x8 Aa = *(const bf16x8*)(M2 + lr * 256 + ((kt * 64 + lq * 16) ^ ((lr & 7) << 4)));
        #pragma unroll
        for (int j = 0; j < 2; ++j) {
            const int nt = w * 2 + j;
            acc[j] = MFMA16(Aa, *(const bf16x8*)(Win2p + ((size_t)(kt * 8 + nt) * 64 + l) * 8), acc[j]);
        }
    }
    __syncthreads();   // all M2 reads done before overwrite with n2 tile
    #pragma unroll
    for (int j = 0; j < 2; ++j) {
        const int nt = w * 2 + j, col = nt * 16 + lr;
        #pragma unroll
        for (int i = 0; i < 4; ++i) {
            const int row = lq * 4 + i;
            const float v = fmaxf(acc[j][i] + gproj_n[(size_t)ngv[i] * 128 + col], 0.f);
            *(unsigned short*)(M2 + row * 256 + ((col * 2) ^ ((row & 7) << 4))) = f2bf(v);
        }
    }
    __syncthreads();
    {
        const int flat = tid * 16;                    // 16 rows x 256B = 4 KB
        const int row = flat >> 8, colb = flat & 255;
        bf16x8 v = *(const bf16x8*)(M2 + row * 256 + (colb ^ ((row & 7) << 4)));
        *(bf16x8*)(n2g + (size_t)(n0 + row) * 128 + (colb >> 1)) = v;
    }
}

// -------------------------------------------------------------- global block
// 8 waves/graph for stream depth; per-graph means over contiguous ranges.
extern "C" __global__ void __launch_bounds__(512)
k_global(const float* __restrict__ global_feats,
         const float* __restrict__ Ugn, const float* __restrict__ Uge,
         const float* __restrict__ Ugg, const float* __restrict__ bg,
         const float* __restrict__ Wm, const float* __restrict__ bm,
         const float* __restrict__ Ws, const float* __restrict__ bs,
         const unsigned short* __restrict__ n2g,
         const unsigned short* __restrict__ e2g,
         const int* __restrict__ offN, const int* __restrict__ offE,
         float* __restrict__ out)
{
    __shared__ float redn[32][128], rede[32][128];
    __shared__ float mn[128], me[128], gs[256];
    const int b = blockIdx.x, tid = threadIdx.x;
    const int c = tid & 15, rp = tid >> 4;     // 8 cols/thread, 32 rows in flight
    float sn[8] = {0.f, 0.f, 0.f, 0.f, 0.f, 0.f, 0.f, 0.f};
    float se[8] = {0.f, 0.f, 0.f, 0.f, 0.f, 0.f, 0.f, 0.f};
    const int nb = offN[b], ne = offN[b + 1];
    for (int r = nb + rp; r < ne; r += 32) {
        bf16x8 v = *(const bf16x8*)(n2g + (size_t)r * 128 + c * 8);
        #pragma unroll
        for (int j = 0; j < 8; ++j) sn[j] += bfs(v[j]);
    }
    const int eb = offE[b], ee = offE[b + 1];
    for (int r = eb + rp; r < ee; r += 32) {
        bf16x8 v = *(const bf16x8*)(e2g + (size_t)r * 128 + c * 8);
        #pragma unroll
        for (int j = 0; j < 8; ++j) se[j] += bfs(v[j]);
    }
    #pragma unroll
    for (int j = 0; j < 8; ++j) { redn[rp][c * 8 + j] = sn[j]; rede[rp][c * 8 + j] = se[j]; }
    __syncthreads();
    if (tid < 128) {
        float s = 0.f;
        #pragma unroll
        for (int k = 0; k < 32; ++k) s += redn[k][tid];
        mn[tid] = s / fmaxf((float)(ne - nb), 1.0f);
    } else if (tid < 256) {
        const int t = tid - 128;
        float s = 0.f;
        #pragma unroll
        for (int k = 0; k < 32; ++k) s += rede[k][t];
        me[t] = s / fmaxf((float)(ee - eb), 1.0f);
    }
    __syncthreads();

    if (tid < 256) {
        const int h = tid;   // H = 256
        float u = bg[h];
        for (int k = 0; k < 128; ++k) u = fmaf(mn[k], Ugn[k * 256 + h], u);
        for (int k = 0; k < 128; ++k) u = fmaf(me[k], Uge[k * 256 + h], u);
        #pragma unroll
        for (int j = 0; j < GF; ++j) u = fmaf(global_feats[b * GF + j], Ugg[j * 256 + h], u);
        gs[h] = fmaxf(u, 0.0f);
    }
    __syncthreads();

    if (tid < 16) {
        const int a = tid & 7;
        const int which = tid >> 3;      // 0 = mean, 1 = log_std
        const float* W = which ? Ws : Wm;
        float acc = which ? bs[a] : bm[a];
        for (int k = 0; k < 256; ++k) acc = fmaf(gs[k], W[k * 8 + a], acc);
        if (which) acc = fminf(fmaxf(acc, -20.0f), 2.0f);
        out[which * 2048 + b * 8 + a] = acc;
    }
}

extern "C" void kernel_launch(void* const* d_in, const int* in_sizes, int n_in,
                              void* d_out, int out_size, void* d_ws, size_t ws_size,
                              hipStream_t stream)
{
    (void)in_sizes; (void)n_in; (void)out_size; (void)ws_size;
    const float* node_feats   = (const float*)d_in[0];
    const float* edge_feats   = (const float*)d_in[1];
    const float* global_feats = (const float*)d_in[2];
    const int*   receivers    = (const int*)d_in[3];
    const int*   node_graph   = (const int*)d_in[4];
    const int*   edge_graph   = (const int*)d_in[5];
    const float* We1 = (const float*)d_in[6];
    const float* be1 = (const float*)d_in[7];
    const float* Wn1 = (const float*)d_in[8];
    const float* Win1= (const float*)d_in[9];
    const float* bn1 = (const float*)d_in[10];
    const float* We2 = (const float*)d_in[11];
    const float* Weg2= (const float*)d_in[12];
    const float* be2 = (const float*)d_in[13];
    const float* Wn2 = (const float*)d_in[14];
    const float* Win2= (const float*)d_in[15];
    const float* Wng2= (const float*)d_in[16];
    const float* bn2 = (const float*)d_in[17];
    const float* Ugn = (const float*)d_in[18];
    const float* Uge = (const float*)d_in[19];
    const float* Ugg = (const float*)d_in[20];
    const float* bg  = (const float*)d_in[21];
    const float* Wm  = (const float*)d_in[22];
    const float* bm  = (const float*)d_in[23];
    const float* Ws  = (const float*)d_in[24];
    const float* bs  = (const float*)d_in[25];

    char* p = (char*)d_ws;
    auto alloc = [&](size_t bytes) -> char* {
        char* r = p; p += (bytes + 255) & ~(size_t)255; return r;
    };
    // zeroed region (contiguous, at the front)
    int* cntR  = (int*)alloc(16384 * 4);
    int* curR  = (int*)alloc(16384 * 4);
    const size_t zero_bytes = (size_t)(p - (char*)d_ws);
    // overwritten-every-call region
    int* offR = (int*)alloc(16385 * 4);
    int* bsum = (int*)alloc(16 * 4);
    int* offN = (int*)alloc(257 * 4);
    int* offE = (int*)alloc(257 * 4);
    int* perm = (int*)alloc((size_t)N_EDGES * 4);
    float* gproj_e = (float*)alloc((size_t)BGR * 128 * 4);
    float* gproj_n = (float*)alloc((size_t)BGR * 128 * 4);
    unsigned short* We1p  = (unsigned short*)alloc((size_t)32 * 256 * 2);
    unsigned short* We2p  = (unsigned short*)alloc((size_t)256 * 128 * 2);
    unsigned short* Wn1p  = (unsigned short*)alloc((size_t)64 * 256 * 2);
    unsigned short* Win1p = (unsigned short*)alloc((size_t)256 * 256 * 2);
    unsigned short* Wn2p  = (unsigned short*)alloc((size_t)256 * 128 * 2);
    unsigned short* Win2p = (unsigned short*)alloc((size_t)128 * 128 * 2);
    unsigned short* e1p   = (unsigned short*)alloc((size_t)N_EDGES * 256 * 2);
    unsigned short* e2p   = (unsigned short*)alloc((size_t)N_EDGES * 128 * 2);
    unsigned short* e2g   = (unsigned short*)alloc((size_t)N_EDGES * 128 * 2);
    unsigned short* n2g   = (unsigned short*)alloc((size_t)N_NODES * 128 * 2);

    hipMemsetAsync(d_ws, 0, zero_bytes, stream);

    k_prep<<<726, 256, 0, stream>>>(
        We1, We2, Wn1, Win1, Wn2, Win2,
        We1p, We2p, Wn1p, Win1p, Wn2p, Win2p,
        global_feats, Weg2, be2, Wng2, bn2, gproj_e, gproj_n,
        receivers, cntR, node_graph, edge_graph, offN, offE);
    k_scanA<<<16, 256, 0, stream>>>(cntR, offR, bsum);
    k_scanB<<<65, 256, 0, stream>>>(offR, bsum);
    k_scatter<<<N_EDGES / 256, 256, 0, stream>>>(receivers, offR, curR, perm);
    k_edge<<<N_EDGES / 64, 256, 0, stream>>>(
        edge_feats, perm, edge_graph, We1p, We2p, be1, gproj_e, e1p, e2p, e2g);
    k_nodeagg<<<N_NODES / 16, 256, 0, stream>>>(
        node_feats, node_graph, offR, e1p, e2p,
        Wn1p, Win1p, Wn2p, Win2p, bn1, gproj_n, n2g);
    k_global<<<BGR, 512, 0, stream>>>(
        global_feats, Ugn, Uge, Ugg, bg, Wm, bm, Ws, bs,
        n2g, e2g, offN, offE, (float*)d_out);
}